// Round 3
// baseline (10218.647 us; speedup 1.0000x reference)
//
#include <hip/hip_runtime.h>
#include <hip/hip_bf16.h>

#define NN 8192
#define NCOLS 101      // y + 100 probes
#define CPW 112        // compute columns (7 x 16)
#define CPAD 128       // staged columns (zero-padded)
#define BM 64
#define KSPL 4
#define KCH (NN / KSPL)    // 2048 fp8 elems (=bytes) per split
#define NSTEP (KCH / 128)  // 16 steps of BK=128
#define PITER 30

typedef __attribute__((ext_vector_type(4))) float f32x4;

__device__ __forceinline__ void async_copy16(const void* g, void* l) {
  __builtin_amdgcn_global_load_lds(
      (const __attribute__((address_space(1))) unsigned int*)g,
      (__attribute__((address_space(3))) unsigned int*)l, 16, 0, 0);
}

__device__ __forceinline__ unsigned int pack_fp8x4(float x, float y, float z, float w) {
  unsigned int v = __builtin_amdgcn_cvt_pk_fp8_f32(x, y, 0, false);
  v = __builtin_amdgcn_cvt_pk_fp8_f32(z, w, v, true);
  return v;
}

// valid result on thread 0 only
__device__ __forceinline__ float block_sum(float v) {
  #pragma unroll
  for (int o = 32; o > 0; o >>= 1) v += __shfl_down(v, o);
  __shared__ float sw[4];
  int w = threadIdx.x >> 6;
  if ((threadIdx.x & 63) == 0) sw[w] = v;
  __syncthreads();
  float r = 0.f;
  if (threadIdx.x < 4) r = sw[threadIdx.x];
  r += __shfl_down(r, 2);
  r += __shfl_down(r, 1);
  return r;
}

// ---------------- GEMM: Vp[kz] = K[rb rows] @ Phat (fp8 MFMA), + pv atomics ----------------
// LDS rows are 128 B (BK=128 fp8). 16B blocks XOR-swizzled: LDS (row, g) holds global
// 16B-seg g^(row&7). Fragment ds_read_b64 then hits banks 2-way (free, m136).
__global__ __launch_bounds__(256, 2) void gemm_kernel(
    const unsigned char* __restrict__ Kb,
    const unsigned char* __restrict__ Pb,
    const float* __restrict__ Pf,
    const float* __restrict__ SCit,
    float* __restrict__ Vp,
    float* __restrict__ pv) {
  __shared__ __align__(16) unsigned char sA[BM * 128];     // 8 KB
  __shared__ __align__(16) unsigned char sB[CPAD * 128];   // 16 KB
  __shared__ __align__(16) float sC[BM * 113];             // 28.9 KB

  int bx = blockIdx.x;
  int rb = bx & 127;
  int kz = bx >> 7;
  int tid = threadIdx.x;
  int lane = tid & 63;
  int w = tid >> 6;
  int r0 = rb * BM;
  int k0 = kz * KCH;      // byte offset into K row / P col
  int lrow = lane >> 3;   // 0..7
  int lseg = lane & 7;    // 16B slot within 128B row
  int gseg = lseg ^ lrow;
  int mm = lane & 15;
  int quad = lane >> 4;

  f32x4 acc[7];
  #pragma unroll
  for (int i = 0; i < 7; ++i) acc[i] = (f32x4){0.f, 0.f, 0.f, 0.f};

  for (int s = 0; s < NSTEP; ++s) {
    int kk = k0 + s * 128;
    #pragma unroll
    for (int q = 0; q < 2; ++q) {  // A: wave w stages rows w*16 + q*8 + lrow
      int rl = w * 16 + q * 8 + lrow;
      async_copy16(Kb + (size_t)(r0 + rl) * NN + kk + gseg * 16,
                   (char*)sA + (size_t)(w * 16 + q * 8) * 128);
    }
    #pragma unroll
    for (int q = 0; q < 4; ++q) {  // B: wave w stages cols w*32 + q*8 + lrow
      int cl = w * 32 + q * 8 + lrow;
      async_copy16(Pb + (size_t)cl * NN + kk + gseg * 16,
                   (char*)sB + (size_t)(w * 32 + q * 8) * 128);
    }
    __syncthreads();
    int arow = w * 16 + mm;
    #pragma unroll
    for (int kh = 0; kh < 4; ++kh) {
      int seg16 = kh * 2 + (quad >> 1);
      long long aF = *(const long long*)(sA + arow * 128 +
                     ((seg16 ^ (arow & 7)) << 4) + ((quad & 1) << 3));
      #pragma unroll
      for (int ct = 0; ct < 7; ++ct) {
        int bcol = ct * 16 + mm;
        long long bF = *(const long long*)(sB + bcol * 128 +
                       ((seg16 ^ (bcol & 7)) << 4) + ((quad & 1) << 3));
        acc[ct] = __builtin_amdgcn_mfma_f32_16x16x32_fp8_fp8(aF, bF, acc[ct], 0, 0, 0);
      }
    }
    __syncthreads();
  }
  // epilogue: transpose through LDS (C/D layout: n=lane&15, m=quad*4+reg)
  #pragma unroll
  for (int ct = 0; ct < 7; ++ct)
    #pragma unroll
    for (int r = 0; r < 4; ++r)
      sC[(w * 16 + quad * 4 + r) * 113 + ct * 16 + mm] = acc[ct][r];
  __syncthreads();
  float* Vout = Vp + (size_t)kz * ((size_t)CPW * NN);
  for (int idx = tid; idx < BM * CPW; idx += 256) {
    int col = idx >> 6;
    int row = idx & 63;
    if (col < NCOLS)
      Vout[(size_t)col * NN + r0 + row] = sC[row * 113 + col] * SCit[col];
  }
  // pv partial: wave g handles cols {g, g+4, ...}; lanes = rows (coalesced P reads)
  int rr = tid & 63;
  int g = tid >> 6;
  for (int j = 0; j < 28; ++j) {
    int c = g + j * 4;
    float prod = 0.f;
    if (c < NCOLS)
      prod = sC[rr * 113 + c] * SCit[c] * Pf[(size_t)c * NN + r0 + rr];
    #pragma unroll
    for (int o = 32; o > 0; o >>= 1) prod += __shfl_down(prod, o);
    if (rr == 0 && c < NCOLS) atomicAdd(pv + c, prod);
  }
}

// ---------------- alpha; V=sum(Vp); R -= a*V; X0 += a*P(:,0); rs_new = |R|^2 ----------------
__global__ void update1_kernel(const float* __restrict__ Vp,
                               const float* __restrict__ Pf,
                               float* __restrict__ R,
                               float* __restrict__ X0,
                               const float* __restrict__ pv,
                               const float* __restrict__ rs,
                               float* __restrict__ rs_new,
                               float* __restrict__ alphas) {
  const size_t SPL = (size_t)CPW * NN;
  int c = blockIdx.y;
  float alpha = rs[c] / pv[c];
  size_t off = (size_t)c * NN + blockIdx.x * 1024 + threadIdx.x * 4;
  float4 a = *(const float4*)(Vp + off);
  float4 b = *(const float4*)(Vp + SPL + off);
  float4 d = *(const float4*)(Vp + 2 * SPL + off);
  float4 e = *(const float4*)(Vp + 3 * SPL + off);
  float4 v;
  v.x = a.x + b.x + d.x + e.x;
  v.y = a.y + b.y + d.y + e.y;
  v.z = a.z + b.z + d.z + e.z;
  v.w = a.w + b.w + d.w + e.w;
  float4 r = *(float4*)(R + off);
  r.x -= alpha * v.x; r.y -= alpha * v.y; r.z -= alpha * v.z; r.w -= alpha * v.w;
  *(float4*)(R + off) = r;
  if (c == 0) {
    size_t xo = blockIdx.x * 1024 + threadIdx.x * 4;
    float4 x = *(float4*)(X0 + xo);
    float4 p = *(const float4*)(Pf + off);
    x.x += alpha * p.x; x.y += alpha * p.y; x.z += alpha * p.z; x.w += alpha * p.w;
    *(float4*)(X0 + xo) = x;
  }
  float rn = r.x * r.x + r.y * r.y + r.z * r.z + r.w * r.w;
  float tot = block_sum(rn);
  if (threadIdx.x == 0) {
    atomicAdd(rs_new + c, tot);
    if (blockIdx.x == 0) alphas[c] = alpha;
  }
}

// ---------------- beta; P = R + b*P; Phat = fp8(P/scale); scale bookkeeping ----------------
__global__ void update2_kernel(const float* __restrict__ R,
                               float* __restrict__ P,
                               unsigned char* __restrict__ Pb,
                               const float* __restrict__ rs,
                               const float* __restrict__ rs_new,
                               const float* __restrict__ PNold,
                               float* __restrict__ PNnew,
                               float* __restrict__ SCnew,
                               float* __restrict__ betas) {
  int c = blockIdx.y;
  float rsn = rs_new[c];
  float beta = rsn / rs[c];
  float pnn = rsn + beta * beta * PNold[c];           // ||P_new||^2 (CG identity)
  float sc = exp2f(roundf(0.5f * log2f(pnn * (1.f / 8192.f))));
  float inv = 1.f / sc;
  size_t off = (size_t)c * NN + blockIdx.x * 1024 + threadIdx.x * 4;
  float4 r = *(const float4*)(R + off);
  float4 p = *(float4*)(P + off);
  p.x = r.x + beta * p.x; p.y = r.y + beta * p.y;
  p.z = r.z + beta * p.z; p.w = r.w + beta * p.w;
  *(float4*)(P + off) = p;
  *(unsigned int*)(Pb + off) = pack_fp8x4(p.x * inv, p.y * inv, p.z * inv, p.w * inv);
  if (threadIdx.x == 0 && blockIdx.x == 0) {
    betas[c] = beta;
    PNnew[c] = pnn;
    SCnew[c] = sc;
  }
}

// ---------------- init ----------------
__global__ void cast_k_kernel(const float* __restrict__ K, unsigned char* __restrict__ Kb) {
  size_t i = ((size_t)blockIdx.x * 256 + threadIdx.x) * 4;
  size_t stride = (size_t)gridDim.x * 1024;
  for (; i < (size_t)NN * NN; i += stride) {
    float4 f = *(const float4*)(K + i);
    *(unsigned int*)(Kb + i) = pack_fp8x4(f.x, f.y, f.z, f.w);
  }
}

__global__ void init_vec_kernel(const float* __restrict__ y, const float* __restrict__ Z,
                                float* __restrict__ P, float* __restrict__ R,
                                unsigned char* __restrict__ Pb) {
  int c = blockIdx.y;
  int i = blockIdx.x * 256 + threadIdx.x;
  float val = (c == 0) ? y[i] : Z[(size_t)i * 100 + (c - 1)];
  size_t off = (size_t)c * NN + i;
  P[off] = val;
  R[off] = val;
  Pb[off] = (unsigned char)(__builtin_amdgcn_cvt_pk_fp8_f32(val, 0.f, 0, false) & 0xFF);
}

#define NSMALL 23424  // RS31 PV30 AL30 BE30 PN31 SC31, x128 floats
__global__ void init_misc_kernel(float* __restrict__ X0, float* __restrict__ smalls,
                                 unsigned char* __restrict__ Pbpad) {
  const int total = 8192 + NSMALL + 27 * NN;
  for (int t = blockIdx.x * 256 + threadIdx.x; t < total; t += gridDim.x * 256) {
    if (t < 8192) X0[t] = 0.f;
    else if (t < 8192 + NSMALL) smalls[t - 8192] = 0.f;
    else Pbpad[t - (8192 + NSMALL)] = 0;
  }
}

__global__ void init_rs_kernel(const float* __restrict__ y, float* __restrict__ rs0,
                               float* __restrict__ pn0, float* __restrict__ sc0) {
  int t = threadIdx.x;
  float s = 0.f;
  for (int i = t; i < NN; i += 256) { float v = y[i]; s += v * v; }
  float tot = block_sum(s);
  if (t == 0) { rs0[0] = tot; pn0[0] = tot; }
  if (t >= 1 && t <= 100) { rs0[t] = (float)NN; pn0[t] = (float)NN; }
  if (t < 128) sc0[t] = 1.f;
}

// ---------------- SLQ: Sturm bisection + Gauss-weight recurrence, fp64 ----------------
__global__ __launch_bounds__(64, 1) void slq_kernel(
    const float* __restrict__ AL, const float* __restrict__ BE,
    float* __restrict__ QP) {
  __shared__ double sd[PITER], se[PITER];
  int lane = threadIdx.x;
  int c = blockIdx.x + 1;
  if (lane < PITER) {
    double a = (double)AL[lane * 128 + c];
    double dd = 1.0 / a;
    if (lane > 0) {
      double ap = (double)AL[(lane - 1) * 128 + c];
      double bp = (double)BE[(lane - 1) * 128 + c];
      dd += bp / ap;
    }
    sd[lane] = dd;
    double ee = 0.0;
    if (lane < PITER - 1) {
      double b = (double)BE[lane * 128 + c];
      ee = sqrt(b) / a;
    }
    se[lane] = ee;
  }
  __syncthreads();
  double d[PITER], e[PITER];
  #pragma unroll
  for (int i = 0; i < PITER; ++i) { d[i] = sd[i]; e[i] = se[i]; }

  float quadk = 0.f;
  if (lane < PITER) {
    double lo = 1e300, hi = -1e300;
    #pragma unroll
    for (int i = 0; i < PITER; ++i) {
      double r = e[i] + (i > 0 ? e[i - 1] : 0.0);
      lo = fmin(lo, d[i] - r);
      hi = fmax(hi, d[i] + r);
    }
    int k = lane;
    for (int it = 0; it < 48; ++it) {
      double mid = 0.5 * (lo + hi);
      int cnt = 0;
      double q = d[0] - mid;
      cnt += (q < 0.0);
      #pragma unroll
      for (int i = 1; i < PITER; ++i) {
        double aq = fabs(q);
        if (aq < 1e-30) q = (q < 0.0) ? -1e-30 : 1e-30;
        q = d[i] - mid - (e[i - 1] * e[i - 1]) / q;
        cnt += (q < 0.0);
      }
      if (cnt > k) hi = mid; else lo = mid;
    }
    double lam = 0.5 * (lo + hi);
    double e0 = fmax(e[0], 1e-150);
    double vprev = 1.0;
    double vcur = (lam - d[0]) / e0;
    double s = 1.0 + vcur * vcur;
    double scale2 = 1.0;
    #pragma unroll
    for (int i = 1; i < PITER - 1; ++i) {
      double ei = fmax(e[i], 1e-150);
      double vnext = ((lam - d[i]) * vcur - e[i - 1] * vprev) / ei;
      if (fabs(vnext) > 1e150) {
        vnext *= 1e-150; vcur *= 1e-150; s *= 1e-300; scale2 *= 1e-300;
      }
      vprev = vcur; vcur = vnext;
      s += vcur * vcur;
    }
    double w = scale2 / s;
    double lc = lam > 1e-12 ? lam : 1e-12;
    quadk = (float)(w * log(lc));
  }
  #pragma unroll
  for (int o = 32; o > 0; o >>= 1) quadk += __shfl_down(quadk, o);
  if (lane == 0) QP[blockIdx.x] = quadk;
}

// ---------------- final: ydot + combine ----------------
__global__ void final2_kernel(const float* __restrict__ y, const float* __restrict__ X0,
                              const float* __restrict__ QP, float* __restrict__ out) {
  int t = threadIdx.x;
  float s = 0.f;
  for (int i = t; i < NN; i += 256) s += y[i] * X0[i];
  float ydot = block_sum(s);
  __syncthreads();
  float q = (t < 100) ? QP[t] : 0.f;
  float qsum = block_sum(q);
  if (t == 0) {
    float logdet = (float)NN * (qsum * 0.01f);
    out[0] = -0.5f * ydot - 0.5f * logdet - (float)NN * 0.5f * 1.8378770664093454f;
  }
}

extern "C" void kernel_launch(void* const* d_in, const int* in_sizes, int n_in,
                              void* d_out, int out_size, void* d_ws, size_t ws_size,
                              hipStream_t stream) {
  const float* K = (const float*)d_in[0];
  const float* y = (const float*)d_in[1];
  const float* Z = (const float*)d_in[2];
  float* out = (float*)d_out;
  char* ws = (char*)d_ws;
  if (ws_size < 90000000ull) return;  // need ~85.5 MiB

  unsigned char* Kb = (unsigned char*)(ws + 0ull);        // 67,108,864
  unsigned char* Pb = (unsigned char*)(ws + 67108864ull); //  1,048,576 (128 cols)
  float* P   = (float*)(ws + 68157440ull);                //  3,309,568 (101 cols)
  float* R   = (float*)(ws + 71467008ull);                //  3,309,568
  float* Vp  = (float*)(ws + 74776576ull);                // 14,680,064 (4 x 112 cols)
  float* X0  = (float*)(ws + 89456640ull);                //     32,768
  float* SM  = (float*)(ws + 89489408ull);                // small scalar block
  float* RS = SM;               // [31][128]
  float* PV = SM + 3968;        // [30][128]
  float* AL = SM + 7808;        // [30][128]
  float* BE = SM + 11648;       // [30][128]
  float* PN = SM + 15488;       // [31][128]
  float* SC = SM + 19456;       // [31][128]
  float* QP = Vp;               // 100 floats, reused after CG loop

  cast_k_kernel<<<8192, 256, 0, stream>>>(K, Kb);
  init_vec_kernel<<<dim3(32, 101), 256, 0, stream>>>(y, Z, P, R, Pb);
  init_misc_kernel<<<240, 256, 0, stream>>>(X0, SM, Pb + (size_t)NCOLS * NN);
  init_rs_kernel<<<1, 256, 0, stream>>>(y, RS, PN, SC);

  for (int it = 0; it < PITER; ++it) {
    gemm_kernel<<<512, 256, 0, stream>>>(Kb, Pb, P, SC + it * 128, Vp, PV + it * 128);
    update1_kernel<<<dim3(8, 101), 256, 0, stream>>>(Vp, P, R, X0, PV + it * 128,
        RS + it * 128, RS + (it + 1) * 128, AL + it * 128);
    update2_kernel<<<dim3(8, 101), 256, 0, stream>>>(R, P, Pb, RS + it * 128,
        RS + (it + 1) * 128, PN + it * 128, PN + (it + 1) * 128,
        SC + (it + 1) * 128, BE + it * 128);
  }
  slq_kernel<<<100, 64, 0, stream>>>(AL, BE, QP);
  final2_kernel<<<1, 256, 0, stream>>>(y, X0, QP, out);
}

// Round 4
// 2042.946 us; speedup vs baseline: 5.0019x; 5.0019x over previous
//
#include <hip/hip_runtime.h>
#include <hip/hip_bf16.h>

#define NN 8192
#define NCOLS 101      // y + 100 probes
#define CPW 112        // compute columns (7 x 16)
#define CPAD 128       // staged columns (zero-padded)
#define BM 64
#define KSPL 4
#define KCH (NN / KSPL)    // 2048 fp8 elems (=bytes) per split
#define NSTEP (KCH / 128)  // 16 steps of BK=128
#define PITER 30
#define PVLD 104           // pvp row stride (101 rounded up)

typedef __attribute__((ext_vector_type(4))) float f32x4;

__device__ __forceinline__ void async_copy16(const void* g, void* l) {
  __builtin_amdgcn_global_load_lds(
      (const __attribute__((address_space(1))) unsigned int*)g,
      (__attribute__((address_space(3))) unsigned int*)l, 16, 0, 0);
}

__device__ __forceinline__ unsigned int pack_fp8x4(float x, float y, float z, float w) {
  unsigned int v = __builtin_amdgcn_cvt_pk_fp8_f32(x, y, 0, false);
  v = __builtin_amdgcn_cvt_pk_fp8_f32(z, w, v, true);
  return v;
}

// valid result on thread 0 only
__device__ __forceinline__ float block_sum(float v) {
  #pragma unroll
  for (int o = 32; o > 0; o >>= 1) v += __shfl_down(v, o);
  __shared__ float sw[4];
  int w = threadIdx.x >> 6;
  if ((threadIdx.x & 63) == 0) sw[w] = v;
  __syncthreads();
  float r = 0.f;
  if (threadIdx.x < 4) r = sw[threadIdx.x];
  r += __shfl_down(r, 2);
  r += __shfl_down(r, 1);
  return r;
}

// ---------------- GEMM: Vp[kz] = K[rb rows] @ Phat (fp8 MFMA) + pv partials ----------------
// LDS rows are 128 B (BK=128 fp8). 16B blocks XOR-swizzled: LDS (row, g) holds global
// 16B-seg g^(row&7). Fragment ds_read_b64 then hits banks 2-way (free).
// pv partials go to pvp[block][c] as plain stores (NO atomics — 512x101 cross-XCD
// atomicAdds to 4 cache lines serialized the whole device in R3: ~750k cyc).
__global__ __launch_bounds__(256, 2) void gemm_kernel(
    const unsigned char* __restrict__ Kb,
    const unsigned char* __restrict__ Pb,
    const float* __restrict__ Pf,
    const float* __restrict__ SCit,
    float* __restrict__ Vp,
    float* __restrict__ pvp) {
  __shared__ __align__(16) unsigned char sA[BM * 128];     // 8 KB
  __shared__ __align__(16) unsigned char sB[CPAD * 128];   // 16 KB
  __shared__ __align__(16) float sC[BM * 113];             // 28.9 KB

  int bx = blockIdx.x;
  int rb = bx & 127;
  int kz = bx >> 7;
  int tid = threadIdx.x;
  int lane = tid & 63;
  int w = tid >> 6;
  int r0 = rb * BM;
  int k0 = kz * KCH;      // byte offset into K row / P col
  int lrow = lane >> 3;   // 0..7
  int lseg = lane & 7;    // 16B slot within 128B row
  int gseg = lseg ^ lrow;
  int mm = lane & 15;
  int quad = lane >> 4;

  f32x4 acc[7];
  #pragma unroll
  for (int i = 0; i < 7; ++i) acc[i] = (f32x4){0.f, 0.f, 0.f, 0.f};

  for (int s = 0; s < NSTEP; ++s) {
    int kk = k0 + s * 128;
    #pragma unroll
    for (int q = 0; q < 2; ++q) {  // A: wave w stages rows w*16 + q*8 + lrow
      int rl = w * 16 + q * 8 + lrow;
      async_copy16(Kb + (size_t)(r0 + rl) * NN + kk + gseg * 16,
                   (char*)sA + (size_t)(w * 16 + q * 8) * 128);
    }
    #pragma unroll
    for (int q = 0; q < 4; ++q) {  // B: wave w stages cols w*32 + q*8 + lrow
      int cl = w * 32 + q * 8 + lrow;
      async_copy16(Pb + (size_t)cl * NN + kk + gseg * 16,
                   (char*)sB + (size_t)(w * 32 + q * 8) * 128);
    }
    __syncthreads();
    int arow = w * 16 + mm;
    #pragma unroll
    for (int kh = 0; kh < 4; ++kh) {
      int seg16 = kh * 2 + (quad >> 1);
      long long aF = *(const long long*)(sA + arow * 128 +
                     ((seg16 ^ (arow & 7)) << 4) + ((quad & 1) << 3));
      #pragma unroll
      for (int ct = 0; ct < 7; ++ct) {
        int bcol = ct * 16 + mm;
        long long bF = *(const long long*)(sB + bcol * 128 +
                       ((seg16 ^ (bcol & 7)) << 4) + ((quad & 1) << 3));
        acc[ct] = __builtin_amdgcn_mfma_f32_16x16x32_fp8_fp8(aF, bF, acc[ct], 0, 0, 0);
      }
    }
    __syncthreads();
  }
  // epilogue: transpose through LDS (C/D layout: n=lane&15, m=quad*4+reg)
  #pragma unroll
  for (int ct = 0; ct < 7; ++ct)
    #pragma unroll
    for (int r = 0; r < 4; ++r)
      sC[(w * 16 + quad * 4 + r) * 113 + ct * 16 + mm] = acc[ct][r];
  __syncthreads();
  float* Vout = Vp + (size_t)kz * ((size_t)CPW * NN);
  for (int idx = tid; idx < BM * CPW; idx += 256) {
    int col = idx >> 6;
    int row = idx & 63;
    if (col < NCOLS)
      Vout[(size_t)col * NN + r0 + row] = sC[row * 113 + col] * SCit[col];
  }
  // pv partial: wave g handles cols {g, g+4, ...}; lanes = rows (coalesced P reads)
  int rr = tid & 63;
  int g = tid >> 6;
  for (int j = 0; j < 28; ++j) {
    int c = g + j * 4;
    float prod = 0.f;
    if (c < NCOLS)
      prod = sC[rr * 113 + c] * SCit[c] * Pf[(size_t)c * NN + r0 + rr];
    #pragma unroll
    for (int o = 32; o > 0; o >>= 1) prod += __shfl_down(prod, o);
    if (rr == 0 && c < NCOLS) pvp[(size_t)bx * PVLD + c] = prod;
  }
}

// ---------------- alpha; V=sum(Vp); R -= a*V; X0 += a*P(:,0); rs_new = |R|^2 ----------------
__global__ void update1_kernel(const float* __restrict__ Vp,
                               const float* __restrict__ Pf,
                               float* __restrict__ R,
                               float* __restrict__ X0,
                               const float* __restrict__ pvp,
                               const float* __restrict__ rs,
                               float* __restrict__ rs_new,
                               float* __restrict__ alphas) {
  const size_t SPL = (size_t)CPW * NN;
  __shared__ float s_alpha;
  int c = blockIdx.y;
  int t = threadIdx.x;
  // redundant per-block sum of the 512 pv partials (L2-resident, ~free)
  float pvv = pvp[(size_t)t * PVLD + c] + pvp[(size_t)(t + 256) * PVLD + c];
  float pvtot = block_sum(pvv);
  if (t == 0) s_alpha = rs[c] / pvtot;
  __syncthreads();
  float alpha = s_alpha;

  size_t off = (size_t)c * NN + blockIdx.x * 1024 + t * 4;
  float4 a = *(const float4*)(Vp + off);
  float4 b = *(const float4*)(Vp + SPL + off);
  float4 d = *(const float4*)(Vp + 2 * SPL + off);
  float4 e = *(const float4*)(Vp + 3 * SPL + off);
  float4 v;
  v.x = a.x + b.x + d.x + e.x;
  v.y = a.y + b.y + d.y + e.y;
  v.z = a.z + b.z + d.z + e.z;
  v.w = a.w + b.w + d.w + e.w;
  float4 r = *(float4*)(R + off);
  r.x -= alpha * v.x; r.y -= alpha * v.y; r.z -= alpha * v.z; r.w -= alpha * v.w;
  *(float4*)(R + off) = r;
  if (c == 0) {
    size_t xo = blockIdx.x * 1024 + t * 4;
    float4 x = *(float4*)(X0 + xo);
    float4 p = *(const float4*)(Pf + off);
    x.x += alpha * p.x; x.y += alpha * p.y; x.z += alpha * p.z; x.w += alpha * p.w;
    *(float4*)(X0 + xo) = x;
  }
  float rn = r.x * r.x + r.y * r.y + r.z * r.z + r.w * r.w;
  float tot = block_sum(rn);
  if (t == 0) {
    atomicAdd(rs_new + c, tot);
    if (blockIdx.x == 0) alphas[c] = alpha;
  }
}

// ---------------- beta; P = R + b*P; Phat = fp8(P/scale); scale bookkeeping ----------------
__global__ void update2_kernel(const float* __restrict__ R,
                               float* __restrict__ P,
                               unsigned char* __restrict__ Pb,
                               const float* __restrict__ rs,
                               const float* __restrict__ rs_new,
                               const float* __restrict__ PNold,
                               float* __restrict__ PNnew,
                               float* __restrict__ SCnew,
                               float* __restrict__ betas) {
  int c = blockIdx.y;
  float rsn = rs_new[c];
  float beta = rsn / rs[c];
  float pnn = rsn + beta * beta * PNold[c];           // ||P_new||^2 (CG identity)
  float sc = exp2f(roundf(0.5f * log2f(pnn * (1.f / 8192.f))));
  float inv = 1.f / sc;
  size_t off = (size_t)c * NN + blockIdx.x * 1024 + threadIdx.x * 4;
  float4 r = *(const float4*)(R + off);
  float4 p = *(float4*)(P + off);
  p.x = r.x + beta * p.x; p.y = r.y + beta * p.y;
  p.z = r.z + beta * p.z; p.w = r.w + beta * p.w;
  *(float4*)(P + off) = p;
  *(unsigned int*)(Pb + off) = pack_fp8x4(p.x * inv, p.y * inv, p.z * inv, p.w * inv);
  if (threadIdx.x == 0 && blockIdx.x == 0) {
    betas[c] = beta;
    PNnew[c] = pnn;
    SCnew[c] = sc;
  }
}

// ---------------- init ----------------
__global__ void cast_k_kernel(const float* __restrict__ K, unsigned char* __restrict__ Kb) {
  size_t i = ((size_t)blockIdx.x * 256 + threadIdx.x) * 4;
  size_t stride = (size_t)gridDim.x * 1024;
  for (; i < (size_t)NN * NN; i += stride) {
    float4 f = *(const float4*)(K + i);
    *(unsigned int*)(Kb + i) = pack_fp8x4(f.x, f.y, f.z, f.w);
  }
}

__global__ void init_vec_kernel(const float* __restrict__ y, const float* __restrict__ Z,
                                float* __restrict__ P, float* __restrict__ R,
                                unsigned char* __restrict__ Pb) {
  int c = blockIdx.y;
  int i = blockIdx.x * 256 + threadIdx.x;
  float val = (c == 0) ? y[i] : Z[(size_t)i * 100 + (c - 1)];
  size_t off = (size_t)c * NN + i;
  P[off] = val;
  R[off] = val;
  Pb[off] = (unsigned char)(__builtin_amdgcn_cvt_pk_fp8_f32(val, 0.f, 0, false) & 0xFF);
}

#define NSMALL 23424  // RS31 PV30 AL30 BE30 PN31 SC31, x128 floats
__global__ void init_misc_kernel(float* __restrict__ X0, float* __restrict__ smalls,
                                 unsigned char* __restrict__ Pbpad) {
  const int total = 8192 + NSMALL + 27 * NN;
  for (int t = blockIdx.x * 256 + threadIdx.x; t < total; t += gridDim.x * 256) {
    if (t < 8192) X0[t] = 0.f;
    else if (t < 8192 + NSMALL) smalls[t - 8192] = 0.f;
    else Pbpad[t - (8192 + NSMALL)] = 0;
  }
}

__global__ void init_rs_kernel(const float* __restrict__ y, float* __restrict__ rs0,
                               float* __restrict__ pn0, float* __restrict__ sc0) {
  int t = threadIdx.x;
  float s = 0.f;
  for (int i = t; i < NN; i += 256) { float v = y[i]; s += v * v; }
  float tot = block_sum(s);
  if (t == 0) { rs0[0] = tot; pn0[0] = tot; }
  if (t >= 1 && t <= 100) { rs0[t] = (float)NN; pn0[t] = (float)NN; }
  if (t < 128) sc0[t] = 1.f;
}

// ---------------- SLQ: Sturm bisection + Gauss-weight recurrence, fp64 ----------------
__global__ __launch_bounds__(64, 1) void slq_kernel(
    const float* __restrict__ AL, const float* __restrict__ BE,
    float* __restrict__ QP) {
  __shared__ double sd[PITER], se[PITER];
  int lane = threadIdx.x;
  int c = blockIdx.x + 1;
  if (lane < PITER) {
    double a = (double)AL[lane * 128 + c];
    double dd = 1.0 / a;
    if (lane > 0) {
      double ap = (double)AL[(lane - 1) * 128 + c];
      double bp = (double)BE[(lane - 1) * 128 + c];
      dd += bp / ap;
    }
    sd[lane] = dd;
    double ee = 0.0;
    if (lane < PITER - 1) {
      double b = (double)BE[lane * 128 + c];
      ee = sqrt(b) / a;
    }
    se[lane] = ee;
  }
  __syncthreads();
  double d[PITER], e[PITER];
  #pragma unroll
  for (int i = 0; i < PITER; ++i) { d[i] = sd[i]; e[i] = se[i]; }

  float quadk = 0.f;
  if (lane < PITER) {
    double lo = 1e300, hi = -1e300;
    #pragma unroll
    for (int i = 0; i < PITER; ++i) {
      double r = e[i] + (i > 0 ? e[i - 1] : 0.0);
      lo = fmin(lo, d[i] - r);
      hi = fmax(hi, d[i] + r);
    }
    int k = lane;
    for (int it = 0; it < 48; ++it) {
      double mid = 0.5 * (lo + hi);
      int cnt = 0;
      double q = d[0] - mid;
      cnt += (q < 0.0);
      #pragma unroll
      for (int i = 1; i < PITER; ++i) {
        double aq = fabs(q);
        if (aq < 1e-30) q = (q < 0.0) ? -1e-30 : 1e-30;
        q = d[i] - mid - (e[i - 1] * e[i - 1]) / q;
        cnt += (q < 0.0);
      }
      if (cnt > k) hi = mid; else lo = mid;
    }
    double lam = 0.5 * (lo + hi);
    double e0 = fmax(e[0], 1e-150);
    double vprev = 1.0;
    double vcur = (lam - d[0]) / e0;
    double s = 1.0 + vcur * vcur;
    double scale2 = 1.0;
    #pragma unroll
    for (int i = 1; i < PITER - 1; ++i) {
      double ei = fmax(e[i], 1e-150);
      double vnext = ((lam - d[i]) * vcur - e[i - 1] * vprev) / ei;
      if (fabs(vnext) > 1e150) {
        vnext *= 1e-150; vcur *= 1e-150; s *= 1e-300; scale2 *= 1e-300;
      }
      vprev = vcur; vcur = vnext;
      s += vcur * vcur;
    }
    double w = scale2 / s;
    double lc = lam > 1e-12 ? lam : 1e-12;
    quadk = (float)(w * log(lc));
  }
  #pragma unroll
  for (int o = 32; o > 0; o >>= 1) quadk += __shfl_down(quadk, o);
  if (lane == 0) QP[blockIdx.x] = quadk;
}

// ---------------- final: ydot + combine ----------------
__global__ void final2_kernel(const float* __restrict__ y, const float* __restrict__ X0,
                              const float* __restrict__ QP, float* __restrict__ out) {
  int t = threadIdx.x;
  float s = 0.f;
  for (int i = t; i < NN; i += 256) s += y[i] * X0[i];
  float ydot = block_sum(s);
  __syncthreads();
  float q = (t < 100) ? QP[t] : 0.f;
  float qsum = block_sum(q);
  if (t == 0) {
    float logdet = (float)NN * (qsum * 0.01f);
    out[0] = -0.5f * ydot - 0.5f * logdet - (float)NN * 0.5f * 1.8378770664093454f;
  }
}

extern "C" void kernel_launch(void* const* d_in, const int* in_sizes, int n_in,
                              void* d_out, int out_size, void* d_ws, size_t ws_size,
                              hipStream_t stream) {
  const float* K = (const float*)d_in[0];
  const float* y = (const float*)d_in[1];
  const float* Z = (const float*)d_in[2];
  float* out = (float*)d_out;
  char* ws = (char*)d_ws;
  if (ws_size < 89796096ull) return;  // need ~85.6 MiB

  unsigned char* Kb = (unsigned char*)(ws + 0ull);        // 67,108,864
  unsigned char* Pb = (unsigned char*)(ws + 67108864ull); //  1,048,576 (128 cols)
  float* P   = (float*)(ws + 68157440ull);                //  3,309,568 (101 cols)
  float* R   = (float*)(ws + 71467008ull);                //  3,309,568
  float* Vp  = (float*)(ws + 74776576ull);                // 14,680,064 (4 x 112 cols)
  float* X0  = (float*)(ws + 89456640ull);                //     32,768
  float* PVP = (float*)(ws + 89489408ull);                //    212,992 (512 x 104)
  float* SM  = (float*)(ws + 89702400ull);                //     93,696 scalar block
  float* RS = SM;               // [31][128]
  float* AL = SM + 7808;        // [30][128]
  float* BE = SM + 11648;       // [30][128]
  float* PN = SM + 15488;       // [31][128]
  float* SC = SM + 19456;       // [31][128]
  float* QP = Vp;               // 100 floats, reused after CG loop

  cast_k_kernel<<<8192, 256, 0, stream>>>(K, Kb);
  init_vec_kernel<<<dim3(32, 101), 256, 0, stream>>>(y, Z, P, R, Pb);
  init_misc_kernel<<<240, 256, 0, stream>>>(X0, SM, Pb + (size_t)NCOLS * NN);
  init_rs_kernel<<<1, 256, 0, stream>>>(y, RS, PN, SC);

  for (int it = 0; it < PITER; ++it) {
    gemm_kernel<<<512, 256, 0, stream>>>(Kb, Pb, P, SC + it * 128, Vp, PVP);
    update1_kernel<<<dim3(8, 101), 256, 0, stream>>>(Vp, P, R, X0, PVP,
        RS + it * 128, RS + (it + 1) * 128, AL + it * 128);
    update2_kernel<<<dim3(8, 101), 256, 0, stream>>>(R, P, Pb, RS + it * 128,
        RS + (it + 1) * 128, PN + it * 128, PN + (it + 1) * 128,
        SC + (it + 1) * 128, BE + it * 128);
  }
  slq_kernel<<<100, 64, 0, stream>>>(AL, BE, QP);
  final2_kernel<<<1, 256, 0, stream>>>(y, X0, QP, out);
}